// Round 1
// baseline (402.316 us; speedup 1.0000x reference)
//
#include <hip/hip_runtime.h>
#include <stdint.h>

// Koopman autoencoder fused kernels (MI355X / gfx950).
// f16 MFMA (16x16x32) with fp32 accumulate; weights pre-transposed to W^T f16.
// Pred branch de-serialized via Ms = L^{s+1} @ W_dec_inner precompute.

typedef _Float16 h8 __attribute__((ext_vector_type(8)));
typedef _Float16 h4 __attribute__((ext_vector_type(4)));
typedef float    f4 __attribute__((ext_vector_type(4)));

#define ROWS_AUTO 104448   // 2048*51

// half-element offsets inside wt region of ws
#define WT_ENCW      0
#define WT_ENCWOUT   (4*16384)
#define WT_DECW      (5*16384)
#define WT_DECWOUT   (9*16384)
#define WT_WENCI     (10*16384)            // [32][128] padded
#define WT_WDECI     (10*16384 + 4096)     // [128][32] padded

// ws byte offsets
#define MS_OFF_B    0x60000    // 50*128*32 halves = 409600 B
#define ACH_OFF_B   0xC8000    // 50*441 floats
#define FET0_OFF_B  0xE0000    // 2048*32 floats (padded full_enc at t=0)

__device__ __forceinline__ f4 mfma16(h8 a, h8 b, f4 c) {
  return __builtin_amdgcn_mfma_f32_16x16x32_f16(a, b, c, 0, 0, 0);
}
// W buffer: [0,32768). rows n stride 256B, 16B chunks XOR-swizzled by row (G4 fix).
__device__ __forceinline__ int woff(int n, int c) { return n*256 + ((c ^ (n & 7)) << 4); }
// h buffer: [32768,65536), wave-private 8KB (32 rows x 128 halves), same swizzle.
__device__ __forceinline__ int hoff(int w, int rl, int c) { return 32768 + w*8192 + rl*256 + ((c ^ (rl & 7)) << 4); }
// fe buffer: lives in upper 128B halves of W rows (free while narrow mats staged).
__device__ __forceinline__ int foff(int w, int rl, int c) { return (w*32 + rl)*256 + 128 + ((c ^ (rl & 3)) << 4); }

__device__ __forceinline__ h8 cvt8(f4 a, f4 b) {
  h8 r;
  r[0]=(_Float16)a[0]; r[1]=(_Float16)a[1]; r[2]=(_Float16)a[2]; r[3]=(_Float16)a[3];
  r[4]=(_Float16)b[0]; r[5]=(_Float16)b[1]; r[6]=(_Float16)b[2]; r[7]=(_Float16)b[3];
  return r;
}

__device__ __forceinline__ void stage_w_full(char* smem, const _Float16* gW, int tid) {
#pragma unroll
  for (int i = 0; i < 8; ++i) {
    int idx = i*256 + tid;          // 2048 slots = 128 rows x 16 chunks
    int n = idx >> 4, c = idx & 15;
    *(h8*)(smem + woff(n, c)) = *(const h8*)(gW + n*128 + c*8);
  }
}
__device__ __forceinline__ void stage_w_rows32(char* smem, const _Float16* gW, int tid) {
#pragma unroll
  for (int i = 0; i < 2; ++i) {
    int idx = i*256 + tid;          // 512 slots = 32 rows x 16 chunks
    int n = idx >> 4, c = idx & 15;
    *(h8*)(smem + woff(n, c)) = *(const h8*)(gW + n*128 + c*8);
  }
}
__device__ __forceinline__ void stage_w_narrow(char* smem, const _Float16* gW, int tid) {
#pragma unroll
  for (int i = 0; i < 2; ++i) {
    int idx = i*256 + tid;          // 512 slots = 128 rows x 4 chunks (row stride 32 halves)
    int n = idx >> 2, c = idx & 3;
    *(h8*)(smem + woff(n, c)) = *(const h8*)(gW + n*32 + c*8);
  }
}

// [32 rows x 128] @ [128 x 128] per wave: 2 row-tiles x 8 col-tiles x 4 k-steps.
__device__ __forceinline__ void mm_full(const char* smem, int w, int lane, f4 acc[2][8]) {
  int r15 = lane & 15, hi = lane >> 4;
#pragma unroll
  for (int rt = 0; rt < 2; ++rt)
#pragma unroll
    for (int nt = 0; nt < 8; ++nt) acc[rt][nt] = (f4){0.f, 0.f, 0.f, 0.f};
#pragma unroll
  for (int ks = 0; ks < 4; ++ks) {
    int c = ks*4 + hi;
    h8 a0 = *(const h8*)(smem + hoff(w, r15, c));
    h8 a1 = *(const h8*)(smem + hoff(w, 16 + r15, c));
#pragma unroll
    for (int nt = 0; nt < 8; ++nt) {
      h8 b = *(const h8*)(smem + woff(nt*16 + r15, c));
      acc[0][nt] = mfma16(a0, b, acc[0][nt]);
      acc[1][nt] = mfma16(a1, b, acc[1][nt]);
    }
  }
}

// 4 hidden dense+ReLU layers (h in LDS) + output matmul. Leaves raw Wout acc.
__device__ __forceinline__ void run_resblock(char* smem, const _Float16* wtW, const _Float16* wtWout,
                                             const float* __restrict__ gb,
                                             int tid, int w, int lane, f4 acc[2][8]) {
  int r15 = lane & 15, hi = lane >> 4;
  for (int l = 0; l < 4; ++l) {
    stage_w_full(smem, wtW + l*16384, tid);
    __syncthreads();                 // W ready
    mm_full(smem, w, lane, acc);
    __syncthreads();                 // all waves done reading W
#pragma unroll
    for (int nt = 0; nt < 8; ++nt) {
      int n = nt*16 + r15;
      float bv = gb[l*128 + n];
#pragma unroll
      for (int rt = 0; rt < 2; ++rt)
#pragma unroll
        for (int d = 0; d < 4; ++d) {
          int rl = rt*16 + hi*4 + d;             // wave-private rows: no barrier needed
          float v = fmaxf(acc[rt][nt][d] + bv, 0.f);
          *(_Float16*)(smem + hoff(w, rl, n >> 3) + (n & 7)*2) = (_Float16)v;
        }
    }
  }
  stage_w_full(smem, wtWout, tid);
  __syncthreads();
  mm_full(smem, w, lane, acc);
  __syncthreads();
}

// ---------------- prep kernels ----------------

__global__ void k_prep_w(const float* __restrict__ encW, const float* __restrict__ encWout,
                         const float* __restrict__ decW, const float* __restrict__ decWout,
                         const float* __restrict__ wencI, const float* __restrict__ wdecI,
                         _Float16* __restrict__ wt) {
  int m = blockIdx.y;
  int idx = blockIdx.x*256 + threadIdx.x;
  if (m < 10) {
    if (idx >= 16384) return;
    const float* src; _Float16* dst;
    if (m < 4)       { src = encW + m*16384;     dst = wt + WT_ENCW + m*16384; }
    else if (m == 4) { src = encWout;            dst = wt + WT_ENCWOUT; }
    else if (m < 9)  { src = decW + (m-5)*16384; dst = wt + WT_DECW + (m-5)*16384; }
    else             { src = decWout;            dst = wt + WT_DECWOUT; }
    int n = idx >> 7, k = idx & 127;
    dst[idx] = (_Float16)src[k*128 + n];         // W^T[n][k] = W[k][n]
  } else if (m == 10) {                          // W_enc_inner [128][21] -> [32][128] padded
    if (idx >= 32*128) return;
    int n = idx >> 7, k = idx & 127;
    wt[WT_WENCI + idx] = (_Float16)((n < 21) ? wencI[k*21 + n] : 0.f);
  } else {                                       // W_dec_inner [21][128] -> [128][32] padded
    if (idx >= 128*32) return;
    int n = idx >> 5, k = idx & 31;
    wt[WT_WDECI + idx] = (_Float16)((k < 21) ? wdecI[k*128 + n] : 0.f);
  }
}

__global__ __launch_bounds__(512) void k_chain(const float* __restrict__ L, float* __restrict__ ach) {
  __shared__ float A[441], Bs[441];
  int t = threadIdx.x;
  if (t < 441) A[t] = L[t];                      // A_0 = L^1
  __syncthreads();
  for (int s = 0; s < 50; ++s) {
    if (t < 441) ach[s*441 + t] = A[t];
    if (s == 49) break;
    if (t < 441) {
      int i = t / 21, j = t % 21; float a = 0.f;
      for (int k = 0; k < 21; ++k) a += A[i*21 + k] * L[k*21 + j];
      Bs[t] = a;
    }
    __syncthreads();
    if (t < 441) A[t] = Bs[t];
    __syncthreads();
  }
}

__global__ __launch_bounds__(512) void k_ms(const float* __restrict__ ach, const float* __restrict__ wdecI,
                                            _Float16* __restrict__ mst) {
  __shared__ float As[441];
  int s = blockIdx.x, t = threadIdx.x;
  if (t < 441) As[t] = ach[s*441 + t];
  __syncthreads();
  for (int idx = t; idx < 4096; idx += 512) {    // Ms^T [128 n][32 k] padded
    int n = idx >> 5, k = idx & 31;
    float a = 0.f;
    if (k < 21) for (int j = 0; j < 21; ++j) a += As[k*21 + j] * wdecI[j*128 + n];
    mst[(size_t)s*4096 + idx] = (_Float16)a;
  }
}

// ---------------- main fused kernel ----------------

__global__ __launch_bounds__(256, 2) void k_main(
    const float* __restrict__ x, const _Float16* __restrict__ wt,
    const float* __restrict__ enc_b, const float* __restrict__ enc_bout,
    const float* __restrict__ dec_b, const float* __restrict__ dec_bout,
    float* __restrict__ out1, float* __restrict__ out2, float* __restrict__ fet0) {
  __shared__ char smem[65536];
  int tid = threadIdx.x, w = tid >> 6, lane = tid & 63;
  int r15 = lane & 15, hi = lane >> 4;
  int rbase = blockIdx.x*128 + w*32;

  // stage x -> h (f16, swizzled)
#pragma unroll
  for (int i = 0; i < 8; ++i) {
    int rl = i*4 + hi, c = r15;
    const float* src = x + (size_t)(rbase + rl)*128 + c*8;
    f4 v0 = *(const f4*)src; f4 v1 = *(const f4*)(src + 4);
    *(h8*)(smem + hoff(w, rl, c)) = cvt8(v0, v1);
  }

  f4 acc[2][8];
  // ---- encoder res_block ----
  run_resblock(smem, wt + WT_ENCW, wt + WT_ENCWOUT, enc_b, tid, w, lane, acc);

  // part_enc = acc + bout + x ; keep fp32 in pe, write f16 to h
  float pe[2][8][4];
#pragma unroll
  for (int nt = 0; nt < 8; ++nt) {
    int n = nt*16 + r15;
    float bv = enc_bout[n];
#pragma unroll
    for (int rt = 0; rt < 2; ++rt)
#pragma unroll
      for (int d = 0; d < 4; ++d) {
        int rl = rt*16 + hi*4 + d;
        float xv = x[(size_t)(rbase + rl)*128 + n];
        float v = acc[rt][nt][d] + bv + xv;
        pe[rt][nt][d] = v;
        *(_Float16*)(smem + hoff(w, rl, n >> 3) + (n & 7)*2) = (_Float16)v;
      }
  }

  // ---- proj1: full_enc = part_enc @ W_enc_inner (N=32 padded) ----
  stage_w_rows32(smem, wt + WT_WENCI, tid);
  __syncthreads();
  f4 a2[2][2];
#pragma unroll
  for (int rt = 0; rt < 2; ++rt)
#pragma unroll
    for (int nt = 0; nt < 2; ++nt) a2[rt][nt] = (f4){0.f, 0.f, 0.f, 0.f};
#pragma unroll
  for (int ks = 0; ks < 4; ++ks) {
    int c = ks*4 + hi;
    h8 a0 = *(const h8*)(smem + hoff(w, r15, c));
    h8 a1 = *(const h8*)(smem + hoff(w, 16 + r15, c));
#pragma unroll
    for (int nt = 0; nt < 2; ++nt) {
      h8 b = *(const h8*)(smem + woff(nt*16 + r15, c));
      a2[0][nt] = mfma16(a0, b, a2[0][nt]);
      a2[1][nt] = mfma16(a1, b, a2[1][nt]);
    }
  }
  __syncthreads();                    // done reading W_enc_inner

  // stage W_dec_inner (low halves of W rows); write full_enc to fe (upper halves)
  stage_w_narrow(smem, wt + WT_WDECI, tid);
#pragma unroll
  for (int nt = 0; nt < 2; ++nt) {
    int n = nt*16 + r15;
#pragma unroll
    for (int rt = 0; rt < 2; ++rt)
#pragma unroll
      for (int d = 0; d < 4; ++d) {
        int rl = rt*16 + hi*4 + d;
        *(_Float16*)(smem + foff(w, rl, n >> 3) + (n & 7)*2) = (_Float16)a2[rt][nt][d];
      }
  }
  // full_enc at t==0 rows -> ws (fp32, padded [2048][32]; cols 21..31 are exact 0)
#pragma unroll
  for (int rt = 0; rt < 2; ++rt)
#pragma unroll
    for (int d = 0; d < 4; ++d) {
      unsigned rg = (unsigned)(rbase + rt*16 + hi*4 + d);
      if (rg % 51u == 0u) {
        unsigned b = rg / 51u;
        fet0[b*32 + r15]      = a2[rt][0][d];
        fet0[b*32 + 16 + r15] = a2[rt][1][d];
      }
    }
  __syncthreads();                    // W_dec_inner staged

  // ---- proj2: part_dec = full_enc @ W_dec_inner (K=32 padded) ----
#pragma unroll
  for (int rt = 0; rt < 2; ++rt)
#pragma unroll
    for (int nt = 0; nt < 8; ++nt) acc[rt][nt] = (f4){0.f, 0.f, 0.f, 0.f};
  {
    int c = hi;
    h8 a0 = *(const h8*)(smem + foff(w, r15, c));
    h8 a1 = *(const h8*)(smem + foff(w, 16 + r15, c));
#pragma unroll
    for (int nt = 0; nt < 8; ++nt) {
      h8 b = *(const h8*)(smem + woff(nt*16 + r15, c));
      acc[0][nt] = mfma16(a0, b, acc[0][nt]);
      acc[1][nt] = mfma16(a1, b, acc[1][nt]);
    }
  }
  __syncthreads();                    // done reading W_dec_inner

  // pack part_dec to f16 (register saver; also the value fed to dec matmul anyway)
  h4 pd[2][8];
#pragma unroll
  for (int rt = 0; rt < 2; ++rt)
#pragma unroll
    for (int nt = 0; nt < 8; ++nt)
#pragma unroll
      for (int d = 0; d < 4; ++d) pd[rt][nt][d] = (_Float16)acc[rt][nt][d];

  // ---- two decoder res_blocks: st=0 on part_enc -> out2 ; st=1 on part_dec -> out1 ----
  for (int st = 0; st < 2; ++st) {
    run_resblock(smem, wt + WT_DECW, wt + WT_DECWOUT, dec_b, tid, w, lane, acc);
#pragma unroll
    for (int nt = 0; nt < 8; ++nt) {
      int n = nt*16 + r15;
      float bv = dec_bout[n];
#pragma unroll
      for (int rt = 0; rt < 2; ++rt)
#pragma unroll
        for (int d = 0; d < 4; ++d) {
          int rl = rt*16 + hi*4 + d;
          size_t rg = (size_t)(rbase + rl);
          float sk = st ? (float)pd[rt][nt][d] : pe[rt][nt][d];
          float v = acc[rt][nt][d] + bv + sk;
          (st ? out1 : out2)[rg*128 + n] = v;
        }
    }
    if (st == 0) {                    // load part_dec into h for stream A
#pragma unroll
      for (int nt = 0; nt < 8; ++nt) {
        int n = nt*16 + r15;
#pragma unroll
        for (int rt = 0; rt < 2; ++rt)
#pragma unroll
          for (int d = 0; d < 4; ++d) {
            int rl = rt*16 + hi*4 + d;
            *(_Float16*)(smem + hoff(w, rl, n >> 3) + (n & 7)*2) = pd[rt][nt][d];
          }
      }
    }
  }
}

// ---------------- prediction kernel ----------------

__global__ __launch_bounds__(256, 2) void k_pred(
    const float* __restrict__ fet0, const _Float16* __restrict__ wt,
    const _Float16* __restrict__ mst,
    const float* __restrict__ dec_b, const float* __restrict__ dec_bout,
    float* __restrict__ out3) {
  __shared__ char smem[65536];
  int tid = threadIdx.x, w = tid >> 6, lane = tid & 63;
  int r15 = lane & 15, hi = lane >> 4;
  int s = blockIdx.y;
  int bbase = blockIdx.x*128 + w*32;

  // stage full_enc_t0 rows (padded 32) -> h chunks 0..3
#pragma unroll
  for (int i = 0; i < 2; ++i) {
    int rl = i*16 + (lane >> 2), c = lane & 3;
    const float* src = fet0 + (size_t)(bbase + rl)*32 + c*8;
    f4 v0 = *(const f4*)src; f4 v1 = *(const f4*)(src + 4);
    *(h8*)(smem + hoff(w, rl, c)) = cvt8(v0, v1);
  }
  stage_w_narrow(smem, mst + (size_t)s*4096, tid);
  __syncthreads();

  // dec_in = cur @ Ms[s]  (K=32 padded)
  f4 acc[2][8];
#pragma unroll
  for (int rt = 0; rt < 2; ++rt)
#pragma unroll
    for (int nt = 0; nt < 8; ++nt) acc[rt][nt] = (f4){0.f, 0.f, 0.f, 0.f};
  {
    int c = hi;
    h8 a0 = *(const h8*)(smem + hoff(w, r15, c));
    h8 a1 = *(const h8*)(smem + hoff(w, 16 + r15, c));
#pragma unroll
    for (int nt = 0; nt < 8; ++nt) {
      h8 b = *(const h8*)(smem + woff(nt*16 + r15, c));
      acc[0][nt] = mfma16(a0, b, acc[0][nt]);
      acc[1][nt] = mfma16(a1, b, acc[1][nt]);
    }
  }
  __syncthreads();                    // done reading Ms before dec weights staged

  float di[2][8][4];
#pragma unroll
  for (int nt = 0; nt < 8; ++nt) {
    int n = nt*16 + r15;
#pragma unroll
    for (int rt = 0; rt < 2; ++rt)
#pragma unroll
      for (int d = 0; d < 4; ++d) {
        int rl = rt*16 + hi*4 + d;
        float v = acc[rt][nt][d];
        di[rt][nt][d] = v;
        *(_Float16*)(smem + hoff(w, rl, n >> 3) + (n & 7)*2) = (_Float16)v;
      }
  }

  run_resblock(smem, wt + WT_DECW, wt + WT_DECWOUT, dec_b, tid, w, lane, acc);

#pragma unroll
  for (int nt = 0; nt < 8; ++nt) {
    int n = nt*16 + r15;
    float bv = dec_bout[n];
#pragma unroll
    for (int rt = 0; rt < 2; ++rt)
#pragma unroll
      for (int d = 0; d < 4; ++d) {
        int rl = rt*16 + hi*4 + d;
        size_t b = (size_t)(bbase + rl);
        out3[(b*50 + s)*128 + n] = acc[rt][nt][d] + bv + di[rt][nt][d];
      }
  }
}

// ---------------- launch ----------------

extern "C" void kernel_launch(void* const* d_in, const int* in_sizes, int n_in,
                              void* d_out, int out_size, void* d_ws, size_t ws_size,
                              hipStream_t stream) {
  const float* x        = (const float*)d_in[0];
  const float* encW     = (const float*)d_in[1];
  const float* enc_b    = (const float*)d_in[2];
  const float* encWout  = (const float*)d_in[3];
  const float* enc_bout = (const float*)d_in[4];
  const float* decW     = (const float*)d_in[5];
  const float* dec_b    = (const float*)d_in[6];
  const float* decWout  = (const float*)d_in[7];
  const float* dec_bout = (const float*)d_in[8];
  const float* wencI    = (const float*)d_in[9];
  const float* L        = (const float*)d_in[10];
  const float* wdecI    = (const float*)d_in[11];

  char* ws = (char*)d_ws;
  _Float16* wt  = (_Float16*)ws;
  _Float16* mst = (_Float16*)(ws + MS_OFF_B);
  float* ach  = (float*)(ws + ACH_OFF_B);
  float* fet0 = (float*)(ws + FET0_OFF_B);

  float* out1 = (float*)d_out;                       // autoencoder_output
  float* out2 = out1 + (size_t)ROWS_AUTO*128;        // outer_auto_output
  float* out3 = out2 + (size_t)ROWS_AUTO*128;        // predictions [2048][50][128]

  hipLaunchKernelGGL(k_prep_w, dim3(64, 12), dim3(256), 0, stream,
                     encW, encWout, decW, decWout, wencI, wdecI, wt);
  hipLaunchKernelGGL(k_chain, dim3(1), dim3(512), 0, stream, L, ach);
  hipLaunchKernelGGL(k_ms, dim3(50), dim3(512), 0, stream, ach, wdecI, mst);
  hipLaunchKernelGGL(k_main, dim3(816), dim3(256), 0, stream,
                     x, wt, enc_b, enc_bout, dec_b, dec_bout, out1, out2, fet0);
  hipLaunchKernelGGL(k_pred, dim3(16, 50), dim3(256), 0, stream,
                     fet0, wt, mst, dec_b, dec_bout, out3);
}

// Round 2
// 342.362 us; speedup vs baseline: 1.1751x; 1.1751x over previous
//
#include <hip/hip_runtime.h>
#include <stdint.h>

// Koopman autoencoder fused kernels (MI355X / gfx950).
// f16 MFMA (16x16x32) fp32-accum; weights pre-transposed to W^T f16.
// Round 2: register-prefetch of next-phase weights under MFMA (T14),
// nontemporal output stores (L2 hygiene), biases staged to LDS,
// L-chain merged into prep kernel.

typedef _Float16 h8 __attribute__((ext_vector_type(8)));
typedef _Float16 h4 __attribute__((ext_vector_type(4)));
typedef float    f4 __attribute__((ext_vector_type(4)));

#define ROWS_AUTO 104448   // 2048*51

// half-element offsets inside wt region of ws
#define WT_ENCW      0
#define WT_ENCWOUT   (4*16384)
#define WT_DECW      (5*16384)
#define WT_DECWOUT   (9*16384)
#define WT_WENCI     (10*16384)            // [32][128] padded
#define WT_WDECI     (10*16384 + 4096)     // [128][32] padded

// ws byte offsets
#define MS_OFF_B    0x60000    // 50*128*32 halves
#define ACH_OFF_B   0xC8000    // 50*441 floats
#define FET0_OFF_B  0xE0000    // 2048*32 floats

// LDS layout: [0,32K) W buffer, [32K,64K) h (8KB/wave), [64K,64K+5K) biases
#define LDS_BYTES 70656
// bias float offsets in bl
#define B_ENCB   0
#define B_ENCBO  512
#define B_DECB   640
#define B_DECBO  1152

__device__ __forceinline__ f4 mfma16(h8 a, h8 b, f4 c) {
  return __builtin_amdgcn_mfma_f32_16x16x32_f16(a, b, c, 0, 0, 0);
}
// W buffer: rows n stride 256B, 16B chunks XOR-swizzled by row (G4 bank fix).
__device__ __forceinline__ int woff(int n, int c) { return n*256 + ((c ^ (n & 7)) << 4); }
// h buffer: wave-private 8KB (32 rows x 128 halves), same swizzle.
__device__ __forceinline__ int hoff(int w, int rl, int c) { return 32768 + w*8192 + rl*256 + ((c ^ (rl & 7)) << 4); }
// fe buffer: upper 128B halves of W rows (free while narrow mats staged).
__device__ __forceinline__ int foff(int w, int rl, int c) { return (w*32 + rl)*256 + 128 + ((c ^ (rl & 3)) << 4); }

__device__ __forceinline__ h8 cvt8(f4 a, f4 b) {
  h8 r;
  r[0]=(_Float16)a[0]; r[1]=(_Float16)a[1]; r[2]=(_Float16)a[2]; r[3]=(_Float16)a[3];
  r[4]=(_Float16)b[0]; r[5]=(_Float16)b[1]; r[6]=(_Float16)b[2]; r[7]=(_Float16)b[3];
  return r;
}

// ---- weight prefetch: M=1 full 32KB, M=2 rows32 (2KB), M=3 narrow 128x32 (2KB) ----
template<int M>
__device__ __forceinline__ void pf_issue(h8* pf, const _Float16* g, int tid) {
  if constexpr (M == 1) {
#pragma unroll
    for (int i = 0; i < 8; ++i) { int idx = i*256 + tid, n = idx >> 4, c = idx & 15;
      pf[i] = *(const h8*)(g + n*128 + c*8); }
  } else if constexpr (M == 2) {
#pragma unroll
    for (int i = 0; i < 2; ++i) { int idx = i*256 + tid, n = idx >> 4, c = idx & 15;
      pf[i] = *(const h8*)(g + n*128 + c*8); }
  } else if constexpr (M == 3) {
#pragma unroll
    for (int i = 0; i < 2; ++i) { int idx = i*256 + tid, n = idx >> 2, c = idx & 3;
      pf[i] = *(const h8*)(g + n*32 + c*8); }
  }
}
template<int M>
__device__ __forceinline__ void pf_write(const h8* pf, char* smem, int tid) {
  if constexpr (M == 1) {
#pragma unroll
    for (int i = 0; i < 8; ++i) { int idx = i*256 + tid;
      *(h8*)(smem + woff(idx >> 4, idx & 15)) = pf[i]; }
  } else if constexpr (M == 2) {
#pragma unroll
    for (int i = 0; i < 2; ++i) { int idx = i*256 + tid;
      *(h8*)(smem + woff(idx >> 4, idx & 15)) = pf[i]; }
  } else if constexpr (M == 3) {
#pragma unroll
    for (int i = 0; i < 2; ++i) { int idx = i*256 + tid;
      *(h8*)(smem + woff(idx >> 2, idx & 3)) = pf[i]; }
  }
}

// [32 rows x 128] @ [128 x 128] per wave: 2 row-tiles x 8 col-tiles x 4 k-steps.
__device__ __forceinline__ void mm_full(const char* smem, int w, int lane, f4 acc[2][8]) {
  int r15 = lane & 15, hi = lane >> 4;
#pragma unroll
  for (int rt = 0; rt < 2; ++rt)
#pragma unroll
    for (int nt = 0; nt < 8; ++nt) acc[rt][nt] = (f4){0.f, 0.f, 0.f, 0.f};
#pragma unroll
  for (int ks = 0; ks < 4; ++ks) {
    int c = ks*4 + hi;
    h8 a0 = *(const h8*)(smem + hoff(w, r15, c));
    h8 a1 = *(const h8*)(smem + hoff(w, 16 + r15, c));
#pragma unroll
    for (int nt = 0; nt < 8; ++nt) {
      h8 b = *(const h8*)(smem + woff(nt*16 + r15, c));
      acc[0][nt] = mfma16(a0, b, acc[0][nt]);
      acc[1][nt] = mfma16(a1, b, acc[1][nt]);
    }
  }
}

// K=32 matmul reading A from h region (USEH) or fe region.
template<bool USEH>
__device__ __forceinline__ void mm_k32(const char* smem, int w, int lane, f4 acc[2][8]) {
  int r15 = lane & 15, hi = lane >> 4;
#pragma unroll
  for (int rt = 0; rt < 2; ++rt)
#pragma unroll
    for (int nt = 0; nt < 8; ++nt) acc[rt][nt] = (f4){0.f, 0.f, 0.f, 0.f};
  int c = hi;
  h8 a0 = USEH ? *(const h8*)(smem + hoff(w, r15, c))      : *(const h8*)(smem + foff(w, r15, c));
  h8 a1 = USEH ? *(const h8*)(smem + hoff(w, 16 + r15, c)) : *(const h8*)(smem + foff(w, 16 + r15, c));
#pragma unroll
  for (int nt = 0; nt < 8; ++nt) {
    h8 b = *(const h8*)(smem + woff(nt*16 + r15, c));
    acc[0][nt] = mfma16(a0, b, acc[0][nt]);
    acc[1][nt] = mfma16(a1, b, acc[1][nt]);
  }
}

// One full-matmul phase: prefetch next W under the mm, write it after drain.
template<int M>
__device__ __forceinline__ void phaseF(char* smem, int tid, int w, int lane,
                                       f4 acc[2][8], const _Float16* nxt) {
  h8 pf[M == 1 ? 8 : 2];
  if constexpr (M != 0) pf_issue<M>(pf, nxt, tid);
  mm_full(smem, w, lane, acc);
  __syncthreads();                 // all waves done reading current W
  if constexpr (M != 0) pf_write<M>(pf, smem, tid);
  __syncthreads();                 // next W staged
}

// ReLU(acc + b) -> h (wave-private rows; after phase's 2nd barrier is safe)
__device__ __forceinline__ void relu_epi(char* smem, const float* bl, int bo,
                                         int w, int lane, f4 acc[2][8]) {
  int r15 = lane & 15, hi = lane >> 4;
#pragma unroll
  for (int nt = 0; nt < 8; ++nt) {
    int n = nt*16 + r15;
    float bv = bl[bo + n];
#pragma unroll
    for (int rt = 0; rt < 2; ++rt)
#pragma unroll
      for (int d = 0; d < 4; ++d) {
        int rl = rt*16 + hi*4 + d;
        float v = fmaxf(acc[rt][nt][d] + bv, 0.f);
        *(_Float16*)(smem + hoff(w, rl, n >> 3) + (n & 7)*2) = (_Float16)v;
      }
  }
}

// 4 dec hidden layers + Wout, with weight prefetch chain. FINALPF: re-prefetch decW L0.
template<bool FINALPF>
__device__ __forceinline__ void dec_run(char* smem, int tid, int w, int lane,
                                        f4 acc[2][8], const _Float16* wt,
                                        const float* bl, int bB) {
  phaseF<1>(smem, tid, w, lane, acc, wt + WT_DECW + 16384);
  relu_epi(smem, bl, bB + 0, w, lane, acc);
  phaseF<1>(smem, tid, w, lane, acc, wt + WT_DECW + 2*16384);
  relu_epi(smem, bl, bB + 128, w, lane, acc);
  phaseF<1>(smem, tid, w, lane, acc, wt + WT_DECW + 3*16384);
  relu_epi(smem, bl, bB + 256, w, lane, acc);
  phaseF<1>(smem, tid, w, lane, acc, wt + WT_DECWOUT);
  relu_epi(smem, bl, bB + 384, w, lane, acc);
  if constexpr (FINALPF) phaseF<1>(smem, tid, w, lane, acc, wt + WT_DECW);
  else                   phaseF<0>(smem, tid, w, lane, acc, nullptr);
}

// ---------------- prep kernel (transpose weights + L-power chain) ----------------

__global__ __launch_bounds__(512) void k_prep(
    const float* __restrict__ encW, const float* __restrict__ encWout,
    const float* __restrict__ decW, const float* __restrict__ decWout,
    const float* __restrict__ wencI, const float* __restrict__ wdecI,
    const float* __restrict__ L,
    _Float16* __restrict__ wt, float* __restrict__ ach) {
  __shared__ float chA[441], chB[441];
  int m = blockIdx.y, tid = threadIdx.x;
  if (m == 12) {                                  // serial L-power chain, 1 block
    if (blockIdx.x != 0) return;
    if (tid < 441) chA[tid] = L[tid];
    __syncthreads();
    for (int s = 0; s < 50; ++s) {
      if (tid < 441) ach[s*441 + tid] = chA[tid];
      if (s == 49) break;
      if (tid < 441) {
        int i = tid / 21, j = tid % 21; float a = 0.f;
        for (int k = 0; k < 21; ++k) a += chA[i*21 + k] * L[k*21 + j];
        chB[tid] = a;
      }
      __syncthreads();
      if (tid < 441) chA[tid] = chB[tid];
      __syncthreads();
    }
    return;
  }
  int idx = blockIdx.x*512 + tid;
  if (m < 10) {
    if (idx >= 16384) return;
    const float* src; _Float16* dst;
    if (m < 4)       { src = encW + m*16384;     dst = wt + WT_ENCW + m*16384; }
    else if (m == 4) { src = encWout;            dst = wt + WT_ENCWOUT; }
    else if (m < 9)  { src = decW + (m-5)*16384; dst = wt + WT_DECW + (m-5)*16384; }
    else             { src = decWout;            dst = wt + WT_DECWOUT; }
    int n = idx >> 7, k = idx & 127;
    dst[idx] = (_Float16)src[k*128 + n];          // W^T
  } else if (m == 10) {                           // W_enc_inner -> [32][128] padded
    if (idx >= 32*128) return;
    int n = idx >> 7, k = idx & 127;
    wt[WT_WENCI + idx] = (_Float16)((n < 21) ? wencI[k*21 + n] : 0.f);
  } else {                                        // W_dec_inner -> [128][32] padded
    if (idx >= 128*32) return;
    int n = idx >> 5, k = idx & 31;
    wt[WT_WDECI + idx] = (_Float16)((k < 21) ? wdecI[k*128 + n] : 0.f);
  }
}

__global__ __launch_bounds__(512) void k_ms(const float* __restrict__ ach,
                                            const float* __restrict__ wdecI,
                                            _Float16* __restrict__ mst) {
  __shared__ float As[441];
  int s = blockIdx.x, t = threadIdx.x;
  if (t < 441) As[t] = ach[s*441 + t];
  __syncthreads();
  for (int idx = t; idx < 4096; idx += 512) {     // Ms^T [128 n][32 k] padded
    int n = idx >> 5, k = idx & 31;
    float a = 0.f;
    if (k < 21) for (int j = 0; j < 21; ++j) a += As[k*21 + j] * wdecI[j*128 + n];
    mst[(size_t)s*4096 + idx] = (_Float16)a;
  }
}

// ---------------- main fused kernel ----------------

__global__ __launch_bounds__(256, 2) void k_main(
    const float* __restrict__ x, const _Float16* __restrict__ wt,
    const float* __restrict__ enc_b, const float* __restrict__ enc_bout,
    const float* __restrict__ dec_b, const float* __restrict__ dec_bout,
    float* __restrict__ out1, float* __restrict__ out2, float* __restrict__ fet0) {
  __shared__ char smem[LDS_BYTES];
  float* bl = (float*)(smem + 65536);
  int tid = threadIdx.x, w = tid >> 6, lane = tid & 63;
  int r15 = lane & 15, hi = lane >> 4;
  int rbase = blockIdx.x*128 + w*32;

  // prologue: issue W_L0 prefetch, stage x->h + biases, then write W_L0
  h8 pf0[8];
  pf_issue<1>(pf0, wt + WT_ENCW, tid);
#pragma unroll
  for (int i = 0; i < 8; ++i) {
    int rl = i*4 + hi, c = r15;
    const float* src = x + (size_t)(rbase + rl)*128 + c*8;
    f4 v0 = *(const f4*)src; f4 v1 = *(const f4*)(src + 4);
    *(h8*)(smem + hoff(w, rl, c)) = cvt8(v0, v1);
  }
  bl[tid]       = enc_b[tid];
  bl[256 + tid] = enc_b[256 + tid];
  if (tid < 128) bl[B_ENCBO + tid] = enc_bout[tid];
  bl[B_DECB + tid]       = dec_b[tid];
  bl[B_DECB + 256 + tid] = dec_b[256 + tid];
  if (tid < 128) bl[B_DECBO + tid] = dec_bout[tid];
  pf_write<1>(pf0, smem, tid);
  __syncthreads();

  f4 acc[2][8];
  // ---- encoder res_block (prefetch chain: L1,L2,L3,Wout,WencI) ----
  phaseF<1>(smem, tid, w, lane, acc, wt + WT_ENCW + 16384);
  relu_epi(smem, bl, B_ENCB + 0, w, lane, acc);
  phaseF<1>(smem, tid, w, lane, acc, wt + WT_ENCW + 2*16384);
  relu_epi(smem, bl, B_ENCB + 128, w, lane, acc);
  phaseF<1>(smem, tid, w, lane, acc, wt + WT_ENCW + 3*16384);
  relu_epi(smem, bl, B_ENCB + 256, w, lane, acc);
  phaseF<1>(smem, tid, w, lane, acc, wt + WT_ENCWOUT);
  relu_epi(smem, bl, B_ENCB + 384, w, lane, acc);
  phaseF<2>(smem, tid, w, lane, acc, wt + WT_WENCI);

  // part_enc = acc + bout + x : keep f16 in pe, write to h
  h4 pe[2][8];
#pragma unroll
  for (int nt = 0; nt < 8; ++nt) {
    int n = nt*16 + r15;
    float bv = bl[B_ENCBO + n];
#pragma unroll
    for (int rt = 0; rt < 2; ++rt)
#pragma unroll
      for (int d = 0; d < 4; ++d) {
        int rl = rt*16 + hi*4 + d;
        float xv = x[(size_t)(rbase + rl)*128 + n];
        float v = acc[rt][nt][d] + bv + xv;
        pe[rt][nt][d] = (_Float16)v;
        *(_Float16*)(smem + hoff(w, rl, n >> 3) + (n & 7)*2) = (_Float16)v;
      }
  }

  // ---- proj1: full_enc = part_enc @ W_enc_inner (N=32 padded); prefetch WdecI ----
  {
    h8 pfn[2];
    pf_issue<3>(pfn, wt + WT_WDECI, tid);
    f4 a2[2][2];
#pragma unroll
    for (int rt = 0; rt < 2; ++rt)
#pragma unroll
      for (int nt = 0; nt < 2; ++nt) a2[rt][nt] = (f4){0.f, 0.f, 0.f, 0.f};
#pragma unroll
    for (int ks = 0; ks < 4; ++ks) {
      int c = ks*4 + hi;
      h8 a0 = *(const h8*)(smem + hoff(w, r15, c));
      h8 a1 = *(const h8*)(smem + hoff(w, 16 + r15, c));
#pragma unroll
      for (int nt = 0; nt < 2; ++nt) {
        h8 b = *(const h8*)(smem + woff(nt*16 + r15, c));
        a2[0][nt] = mfma16(a0, b, a2[0][nt]);
        a2[1][nt] = mfma16(a1, b, a2[1][nt]);
      }
    }
    __syncthreads();
    pf_write<3>(pfn, smem, tid);
    __syncthreads();
    // full_enc -> fe region (wave-private rows); t==0 rows -> fet0
#pragma unroll
    for (int nt = 0; nt < 2; ++nt) {
      int n = nt*16 + r15;
#pragma unroll
      for (int rt = 0; rt < 2; ++rt)
#pragma unroll
        for (int d = 0; d < 4; ++d) {
          int rl = rt*16 + hi*4 + d;
          *(_Float16*)(smem + foff(w, rl, n >> 3) + (n & 7)*2) = (_Float16)a2[rt][nt][d];
        }
    }
#pragma unroll
    for (int rt = 0; rt < 2; ++rt)
#pragma unroll
      for (int d = 0; d < 4; ++d) {
        unsigned rg = (unsigned)(rbase + rt*16 + hi*4 + d);
        if (rg % 51u == 0u) {
          unsigned b = rg / 51u;
          fet0[b*32 + r15]      = a2[rt][0][d];
          fet0[b*32 + 16 + r15] = a2[rt][1][d];
        }
      }
  }

  // ---- proj2: part_dec = full_enc @ W_dec_inner (K=32); prefetch decW L0 ----
  {
    h8 pfd[8];
    pf_issue<1>(pfd, wt + WT_DECW, tid);
    mm_k32<false>(smem, w, lane, acc);
    __syncthreads();
    pf_write<1>(pfd, smem, tid);
    __syncthreads();
  }
  h4 pd[2][8];
#pragma unroll
  for (int rt = 0; rt < 2; ++rt)
#pragma unroll
    for (int nt = 0; nt < 8; ++nt)
#pragma unroll
      for (int d = 0; d < 4; ++d) pd[rt][nt][d] = (_Float16)acc[rt][nt][d];

  // ---- dec stream B: input h = part_enc -> out2 (re-prefetch decW L0 at end) ----
  dec_run<true>(smem, tid, w, lane, acc, wt, bl, B_DECB);
#pragma unroll
  for (int nt = 0; nt < 8; ++nt) {
    int n = nt*16 + r15;
    float bv = bl[B_DECBO + n];
#pragma unroll
    for (int rt = 0; rt < 2; ++rt)
#pragma unroll
      for (int d = 0; d < 4; ++d) {
        int rl = rt*16 + hi*4 + d;
        size_t rg = (size_t)(rbase + rl);
        float v = acc[rt][nt][d] + bv + (float)pe[rt][nt][d];
        __builtin_nontemporal_store(v, &out2[rg*128 + n]);
        *(_Float16*)(smem + hoff(w, rl, n >> 3) + (n & 7)*2) = pd[rt][nt][d];
      }
  }

  // ---- dec stream A: input h = part_dec -> out1 ----
  dec_run<false>(smem, tid, w, lane, acc, wt, bl, B_DECB);
#pragma unroll
  for (int nt = 0; nt < 8; ++nt) {
    int n = nt*16 + r15;
    float bv = bl[B_DECBO + n];
#pragma unroll
    for (int rt = 0; rt < 2; ++rt)
#pragma unroll
      for (int d = 0; d < 4; ++d) {
        int rl = rt*16 + hi*4 + d;
        size_t rg = (size_t)(rbase + rl);
        float v = acc[rt][nt][d] + bv + (float)pd[rt][nt][d];
        __builtin_nontemporal_store(v, &out1[rg*128 + n]);
      }
  }
}

// ---------------- prediction kernel ----------------

__global__ __launch_bounds__(256, 2) void k_pred(
    const float* __restrict__ fet0, const _Float16* __restrict__ wt,
    const _Float16* __restrict__ mst,
    const float* __restrict__ dec_b, const float* __restrict__ dec_bout,
    float* __restrict__ out3) {
  __shared__ char smem[LDS_BYTES];
  float* bl = (float*)(smem + 65536);
  int tid = threadIdx.x, w = tid >> 6, lane = tid & 63;
  int r15 = lane & 15, hi = lane >> 4;
  int s = blockIdx.y;
  int bbase = blockIdx.x*128 + w*32;

  // issue decW L0 prefetch first; stage fet0 -> h, Ms -> narrow W, biases
  h8 pfd[8];
  pf_issue<1>(pfd, wt + WT_DECW, tid);
  h8 pfm[2];
  pf_issue<3>(pfm, mst + (size_t)s*4096, tid);
#pragma unroll
  for (int i = 0; i < 2; ++i) {
    int rl = i*16 + (lane >> 2), c = lane & 3;
    const float* src = fet0 + (size_t)(bbase + rl)*32 + c*8;
    f4 v0 = *(const f4*)src; f4 v1 = *(const f4*)(src + 4);
    *(h8*)(smem + hoff(w, rl, c)) = cvt8(v0, v1);
  }
  bl[tid]       = dec_b[tid];
  bl[256 + tid] = dec_b[256 + tid];
  if (tid < 128) bl[512 + tid] = dec_bout[tid];
  pf_write<3>(pfm, smem, tid);
  __syncthreads();

  // dec_in = cur @ Ms[s] (K=32), then write decW L0
  f4 acc[2][8];
  mm_k32<true>(smem, w, lane, acc);
  __syncthreads();
  pf_write<1>(pfd, smem, tid);
  __syncthreads();

  h4 di[2][8];
#pragma unroll
  for (int nt = 0; nt < 8; ++nt) {
    int n = nt*16 + r15;
#pragma unroll
    for (int rt = 0; rt < 2; ++rt)
#pragma unroll
      for (int d = 0; d < 4; ++d) {
        int rl = rt*16 + hi*4 + d;
        _Float16 v = (_Float16)acc[rt][nt][d];
        di[rt][nt][d] = v;
        *(_Float16*)(smem + hoff(w, rl, n >> 3) + (n & 7)*2) = v;
      }
  }

  dec_run<false>(smem, tid, w, lane, acc, wt, bl, 0);

#pragma unroll
  for (int nt = 0; nt < 8; ++nt) {
    int n = nt*16 + r15;
    float bv = bl[512 + n];
#pragma unroll
    for (int rt = 0; rt < 2; ++rt)
#pragma unroll
      for (int d = 0; d < 4; ++d) {
        int rl = rt*16 + hi*4 + d;
        size_t b = (size_t)(bbase + rl);
        float v = acc[rt][nt][d] + bv + (float)di[rt][nt][d];
        __builtin_nontemporal_store(v, &out3[(b*50 + s)*128 + n]);
      }
  }
}

// ---------------- launch ----------------

extern "C" void kernel_launch(void* const* d_in, const int* in_sizes, int n_in,
                              void* d_out, int out_size, void* d_ws, size_t ws_size,
                              hipStream_t stream) {
  const float* x        = (const float*)d_in[0];
  const float* encW     = (const float*)d_in[1];
  const float* enc_b    = (const float*)d_in[2];
  const float* encWout  = (const float*)d_in[3];
  const float* enc_bout = (const float*)d_in[4];
  const float* decW     = (const float*)d_in[5];
  const float* dec_b    = (const float*)d_in[6];
  const float* decWout  = (const float*)d_in[7];
  const float* dec_bout = (const float*)d_in[8];
  const float* wencI    = (const float*)d_in[9];
  const float* L        = (const float*)d_in[10];
  const float* wdecI    = (const float*)d_in[11];

  char* ws = (char*)d_ws;
  _Float16* wt  = (_Float16*)ws;
  _Float16* mst = (_Float16*)(ws + MS_OFF_B);
  float* ach  = (float*)(ws + ACH_OFF_B);
  float* fet0 = (float*)(ws + FET0_OFF_B);

  float* out1 = (float*)d_out;                       // autoencoder_output
  float* out2 = out1 + (size_t)ROWS_AUTO*128;        // outer_auto_output
  float* out3 = out2 + (size_t)ROWS_AUTO*128;        // predictions [2048][50][128]

  hipLaunchKernelGGL(k_prep, dim3(32, 13), dim3(512), 0, stream,
                     encW, encWout, decW, decWout, wencI, wdecI, L, wt, ach);
  hipLaunchKernelGGL(k_ms, dim3(50), dim3(512), 0, stream, ach, wdecI, mst);
  hipLaunchKernelGGL(k_main, dim3(816), dim3(256), 0, stream,
                     x, wt, enc_b, enc_bout, dec_b, dec_bout, out1, out2, fet0);
  hipLaunchKernelGGL(k_pred, dim3(16, 50), dim3(256), 0, stream,
                     fet0, wt, mst, dec_b, dec_bout, out3);
}